// Round 4
// baseline (114.381 us; speedup 1.0000x reference)
//
#include <hip/hip_runtime.h>
#include <math.h>

#define BB 512
#define CC 256
#define RPB 4                // rows owned per block
#define GRID (BB / RPB)      // 128 blocks
typedef unsigned long long u64;

// Scratch in device globals (R6: d_ws poison is unconditional, so d_ws vs
// globals is neutral; globals keep the harness surface minimal).
__device__ float g_bceP[BB];
__device__ float g_mskP[BB];
__device__ float g_contrib[BB];

__device__ inline float wave_sum(float v) {
    #pragma unroll
    for (int off = 32; off > 0; off >>= 1) v += __shfl_down(v, off, 64);
    return v;
}
__device__ inline float wave_max(float v) {
    #pragma unroll
    for (int off = 32; off > 0; off >>= 1) v = fmaxf(v, __shfl_down(v, off, 64));
    return v;
}

// ---------------- Fused kernel: pack-all-rows-per-block + own 4 rows --------
// R7: removes K1 and the K1->K2 dispatch boundary with ZERO added sync
// (ledger: every sync-based fusion cost +4..+8us; this one adds none).
// Each block re-packs ALL 512 rows' concept bits into LDS from mc (512 KB,
// L2-served; 128 blocks -> 64 MB aggregate ~ 2us) via int4 loads + 4 ballots
// per wave. Bit order is concept-permuted (bit l of plane k = concept 4l+k);
// Jaccard popcounts are permutation-invariant, so results are exact.
// Then the block computes the full softmax/KL row work for its 4 owned rows
// (identical FP order to the known-good K2 -> absmax 0.0) and the BCE
// partials for those rows (identical to K1's per-row layout).
__global__ __launch_bounds__(256) void fused_kernel(
        const int* __restrict__ mc, const float* __restrict__ cl,
        const float* __restrict__ lpi, const float* __restrict__ lpt,
        const float* __restrict__ cis) {
    int tid = threadIdx.x;
    int wave = tid >> 6, lane = tid & 63;

    __shared__ u64   bits[4][BB];    // 16 KB, plane-major (permuted bit order)
    __shared__ float red[4][40];
    __shared__ float Msh[16];

    // ---- pack phase: 4 rows per iteration (one per wave) -------------------
    const int4* mc4 = (const int4*)mc;
    #pragma unroll 8
    for (int r0 = 0; r0 < BB; r0 += 4) {
        int r = r0 + wave;
        int4 v = mc4[r * (CC / 4) + lane];     // 64 lanes x 16B = one row
        u64 p0 = __ballot(v.x == 1);
        u64 p1 = __ballot(v.y == 1);
        u64 p2 = __ballot(v.z == 1);
        u64 p3 = __ballot(v.w == 1);
        if (lane == 0) {
            bits[0][r] = p0; bits[1][r] = p1; bits[2][r] = p2; bits[3][r] = p3;
        }
    }
    __syncthreads();

    // ---- per-owned-row gather: sim (from LDS bits), logits, BCE ------------
    int ibase = blockIdx.x * RPB;
    float a[RPB][2];
    float x0[RPB][2], x1[RPB][2], x2[RPB][2];
    float bces[RPB], msks[RPB];

    #pragma unroll
    for (int rr = 0; rr < RPB; ++rr) {
        int i = ibase + rr;
        u64 m0 = bits[0][i], m1 = bits[1][i], m2 = bits[2][i], m3 = bits[3][i];
        #pragma unroll
        for (int jj = 0; jj < 2; ++jj) {
            int j = tid + jj * 256;
            u64 b0 = bits[0][j], b1 = bits[1][j], b2 = bits[2][j], b3 = bits[3][j];
            int inter = __popcll(m0 & b0) + __popcll(m1 & b1)
                      + __popcll(m2 & b2) + __popcll(m3 & b3);
            int uni   = __popcll(m0 | b0) + __popcll(m1 | b1)
                      + __popcll(m2 | b2) + __popcll(m3 | b3);
            a[rr][jj] = (uni > 0) ? (5.0f * (float)inter / (float)uni) : 0.0f; // sim/T
        }
        size_t off = (size_t)i * BB + tid;
        x0[rr][0] = lpi[off]; x0[rr][1] = lpi[off + 256];
        x1[rr][0] = lpt[off]; x1[rr][1] = lpt[off + 256];
        x2[rr][0] = cis[off]; x2[rr][1] = cis[off + 256];

        int   c  = mc[i * CC + tid];           // L1/L2-hot from pack phase
        float xx = cl[i * CC + tid];
        float mask = (c != -1) ? 1.0f : 0.0f;
        float t    = (c == 1) ? 1.0f : 0.0f;
        bces[rr] = (fmaxf(xx, 0.0f) - xx * t + log1pf(__expf(-fabsf(xx)))) * mask;
        msks[rr] = mask;
    }

    // ---- phase 1: 16 batched maxes (4 rows x 4), one barrier pair ----------
    float mv[16];
    #pragma unroll
    for (int rr = 0; rr < RPB; ++rr) {
        mv[rr * 4 + 0] = fmaxf(a[rr][0], a[rr][1]);
        mv[rr * 4 + 1] = fmaxf(x0[rr][0], x0[rr][1]);
        mv[rr * 4 + 2] = fmaxf(x1[rr][0], x1[rr][1]);
        mv[rr * 4 + 3] = fmaxf(x2[rr][0], x2[rr][1]);
    }
    #pragma unroll
    for (int k = 0; k < 16; ++k) {
        float w = wave_max(mv[k]);
        if (lane == 0) red[wave][k] = w;
    }
    __syncthreads();
    if (tid < 16)
        Msh[tid] = fmaxf(fmaxf(red[0][tid], red[1][tid]),
                         fmaxf(red[2][tid], red[3][tid]));
    __syncthreads();   // Msh visible + red reusable

    float M[16];
    #pragma unroll
    for (int k = 0; k < 16; ++k) M[k] = Msh[k];

    // ---- phase 2: 40 batched sums (4 rows x 10), one barrier pair ----------
    float sv[40];
    #pragma unroll
    for (int rr = 0; rr < RPB; ++rr) {
        int base = rr * 10;
        float e0 = __expf(a[rr][0] - M[rr * 4 + 0]);
        float e1 = __expf(a[rr][1] - M[rr * 4 + 0]);
        sv[base + 0] = e0 + e1;
        sv[base + 1] = e0 * a[rr][0] + e1 * a[rr][1];
        sv[base + 2] = __expf(x0[rr][0] - M[rr * 4 + 1]) + __expf(x0[rr][1] - M[rr * 4 + 1]);
        sv[base + 3] = e0 * x0[rr][0] + e1 * x0[rr][1];
        sv[base + 4] = __expf(x1[rr][0] - M[rr * 4 + 2]) + __expf(x1[rr][1] - M[rr * 4 + 2]);
        sv[base + 5] = e0 * x1[rr][0] + e1 * x1[rr][1];
        sv[base + 6] = __expf(x2[rr][0] - M[rr * 4 + 3]) + __expf(x2[rr][1] - M[rr * 4 + 3]);
        sv[base + 7] = e0 * x2[rr][0] + e1 * x2[rr][1];
        sv[base + 8] = bces[rr];
        sv[base + 9] = msks[rr];
    }
    #pragma unroll
    for (int k = 0; k < 40; ++k) {
        float w = wave_sum(sv[k]);
        if (lane == 0) red[wave][k] = w;
    }
    __syncthreads();

    // ---- finalize: thread rr handles owned row rr --------------------------
    if (tid < RPB) {
        int rr = tid, i = ibase + rr;
        float S[10];
        #pragma unroll
        for (int k = 0; k < 10; ++k)
            S[k] = red[0][rr * 10 + k] + red[1][rr * 10 + k]
                 + red[2][rr * 10 + k] + red[3][rr * 10 + k];
        float Z = S[0], invZ = 1.0f / Z, lZ = logf(Z);
        float m0 = Msh[rr * 4 + 0], m1 = Msh[rr * 4 + 1];
        float m2 = Msh[rr * 4 + 2], m3 = Msh[rr * 4 + 3];
        float ent = S[1] * invZ - m0 - lZ;
        float ci  = S[3] * invZ - m1 - logf(S[2]);
        float ct  = S[5] * invZ - m2 - logf(S[4]);
        float cc  = S[7] * invZ - m3 - logf(S[6]);
        g_contrib[i] = (2.0f * ent - ci - ct) * (0.5f / (float)BB)
                     + 0.2f * (ent - cc) * (1.0f / (float)BB);
        g_bceP[i] = S[8];
        g_mskP[i] = S[9];
    }
}

// ---------------- Kernel 2: final reduction + combine ------------------------
__global__ __launch_bounds__(512) void finalize_kernel(float* __restrict__ out) {
    int tid = threadIdx.x;
    int wave = tid >> 6, lane = tid & 63;
    float c = g_contrib[tid];
    float b = g_bceP[tid];
    float m = g_mskP[tid];
    __shared__ float red[8][3];
    float wc = wave_sum(c), wb = wave_sum(b), wm = wave_sum(m);
    if (lane == 0) { red[wave][0] = wc; red[wave][1] = wb; red[wave][2] = wm; }
    __syncthreads();
    if (tid == 0) {
        float C = 0.0f, Bs = 0.0f, Ms = 0.0f;
        #pragma unroll
        for (int w = 0; w < 8; ++w) { C += red[w][0]; Bs += red[w][1]; Ms += red[w][2]; }
        out[0] = C + 0.2f * (Bs / (Ms + 1e-8f));
    }
}

extern "C" void kernel_launch(void* const* d_in, const int* in_sizes, int n_in,
                              void* d_out, int out_size, void* d_ws, size_t ws_size,
                              hipStream_t stream) {
    const float* lpi = (const float*)d_in[0];   // logits_per_image [512,512]
    const float* lpt = (const float*)d_in[1];   // logits_per_text  [512,512]
    const float* cl  = (const float*)d_in[2];   // concepts_logits  [512,256]
    const float* cis = (const float*)d_in[3];   // concepts_image_similarity [512,512]
    const int*   mc  = (const int*)d_in[4];     // medical_concepts [512,256]

    (void)d_ws; (void)ws_size;   // unused: d_ws poison is unconditional (R6)

    float* out = (float*)d_out;

    fused_kernel<<<GRID, CC, 0, stream>>>(mc, cl, lpi, lpt, cis);
    finalize_kernel<<<1, BB, 0, stream>>>(out);
}

// Round 6
// 69.995 us; speedup vs baseline: 1.6341x; 1.6341x over previous
//
#include <hip/hip_runtime.h>
#include <math.h>

#define BB 512
#define CC 256
typedef unsigned long long u64;

// ---- scratch in MODULE-SCOPE device globals ---------------------------------
// R6: the 256 MiB / ~40us fillBufferAligned that tops every profile is the
// harness re-poisoning d_ws UNCONDITIONALLY each iteration (56% of dur_us) —
// moving scratch off d_ws did not remove it, but is neutral, so scratch stays
// here (minimal harness surface).
__device__ u64   g_bitsP[4 * BB];     // bit-planes, plane-major [c][r]
__device__ float g_bceP[BB];
__device__ float g_mskP[BB];
__device__ float g_contrib[BB];

__device__ inline float wave_sum(float v) {
    #pragma unroll
    for (int off = 32; off > 0; off >>= 1) v += __shfl_down(v, off, 64);
    return v;
}
__device__ inline float wave_max(float v) {
    #pragma unroll
    for (int off = 32; off > 0; off >>= 1) v = fmaxf(v, __shfl_down(v, off, 64));
    return v;
}

// ---------------- Kernel 1: pack bit-planes + per-row BCE partials -----------
// STRUCTURE FROZEN (best-measured 69.6-71.2us config; R9 = resubmit of R8
// after an infra core-dump flake — source identical to the passing R6 run).
// Full structural ledger — every deviation lost:
//   R2 fences +8us | R3 atomic spin +7us | R4 last-block ACQ_REL +6.4us
//   R5 relaxed atomicAdd finalize +4us | R7 zero-sync redundant-pack +43us
//     (128-block grid = 2 waves/CU; 128-step serial load->ballot chain fully
//      latency-exposed. K1's value is packing ONCE at 512-block occupancy.)
// 512 blocks x 256 threads — full chip coverage for the 1 MB mc+cl read.
// One mc load feeds both the ballot-pack and the BCE mask. Plain stores only;
// visibility to K2/K3 via kernel dispatch boundaries.
// bitsP layout: bitsP[c*BB + r] (plane-major -> K2's per-j loads coalesce).
__global__ __launch_bounds__(256) void pack_bce_kernel(
        const int* __restrict__ mc, const float* __restrict__ cl) {
    int i = blockIdx.x, tid = threadIdx.x;
    int wave = tid >> 6, lane = tid & 63;

    int c = mc[i * CC + tid];
    u64 bal = __ballot(c == 1);
    if (lane == 0) g_bitsP[wave * BB + i] = bal;

    float x = cl[i * CC + tid];
    float mask = (c != -1) ? 1.0f : 0.0f;
    float t = (c == 1) ? 1.0f : 0.0f;
    float bce = (fmaxf(x, 0.0f) - x * t + log1pf(__expf(-fabsf(x)))) * mask;

    __shared__ float red[4][2];
    float wb = wave_sum(bce), wm = wave_sum(mask);
    if (lane == 0) { red[wave][0] = wb; red[wave][1] = wm; }
    __syncthreads();
    if (tid == 0) {
        g_bceP[i] = red[0][0] + red[1][0] + red[2][0] + red[3][0];
        g_mskP[i] = red[0][1] + red[1][1] + red[2][1] + red[3][1];
    }
}

// ---------------- Kernel 2: one block per row (256 thr x 2 cols) -------------
// Known-good config: sim held in registers, 12 block reductions batched into
// 2 barrier phases (~5 barriers vs 24).
__global__ __launch_bounds__(256) void row_kernel(
        const float* __restrict__ lpi, const float* __restrict__ lpt,
        const float* __restrict__ cis) {
    int i = blockIdx.x, tid = threadIdx.x;
    int wave = tid >> 6, lane = tid & 63;
    __shared__ float red[4][8];

    // own-row masks (uniform address -> scalar loads)
    u64 m0 = g_bitsP[0 * BB + i], m1 = g_bitsP[1 * BB + i];
    u64 m2 = g_bitsP[2 * BB + i], m3 = g_bitsP[3 * BB + i];

    float a[2];
    #pragma unroll
    for (int jj = 0; jj < 2; ++jj) {
        int j = tid + jj * 256;
        u64 b0 = g_bitsP[0 * BB + j], b1 = g_bitsP[1 * BB + j];
        u64 b2 = g_bitsP[2 * BB + j], b3 = g_bitsP[3 * BB + j];
        int inter = __popcll(m0 & b0) + __popcll(m1 & b1) + __popcll(m2 & b2) + __popcll(m3 & b3);
        int uni   = __popcll(m0 | b0) + __popcll(m1 | b1) + __popcll(m2 | b2) + __popcll(m3 | b3);
        a[jj] = (uni > 0) ? (5.0f * (float)inter / (float)uni) : 0.0f;  // sim/T
    }

    size_t off = (size_t)i * BB + tid;
    float x00 = lpi[off], x01 = lpi[off + 256];
    float x10 = lpt[off], x11 = lpt[off + 256];
    float x20 = cis[off], x21 = cis[off + 256];

    // ---- phase 1: 4 independent maxes, one barrier pair ----
    float mv[4] = { fmaxf(a[0], a[1]), fmaxf(x00, x01), fmaxf(x10, x11), fmaxf(x20, x21) };
    #pragma unroll
    for (int k = 0; k < 4; ++k) {
        float w = wave_max(mv[k]);
        if (lane == 0) red[wave][k] = w;
    }
    __syncthreads();
    float M[4];
    #pragma unroll
    for (int k = 0; k < 4; ++k)
        M[k] = fmaxf(fmaxf(red[0][k], red[1][k]), fmaxf(red[2][k], red[3][k]));
    __syncthreads();   // red reuse

    // ---- phase 2: 8 independent sums, one barrier pair ----
    float e0 = __expf(a[0] - M[0]), e1 = __expf(a[1] - M[0]);
    float sv[8] = { e0 + e1, e0 * a[0] + e1 * a[1],
                    __expf(x00 - M[1]) + __expf(x01 - M[1]), e0 * x00 + e1 * x01,
                    __expf(x10 - M[2]) + __expf(x11 - M[2]), e0 * x10 + e1 * x11,
                    __expf(x20 - M[3]) + __expf(x21 - M[3]), e0 * x20 + e1 * x21 };
    #pragma unroll
    for (int k = 0; k < 8; ++k) {
        float w = wave_sum(sv[k]);
        if (lane == 0) red[wave][k] = w;
    }
    __syncthreads();

    if (tid == 0) {
        float S[8];
        #pragma unroll
        for (int k = 0; k < 8; ++k)
            S[k] = red[0][k] + red[1][k] + red[2][k] + red[3][k];
        float Z = S[0], invZ = 1.0f / Z, lZ = logf(Z);
        float ent = S[1] * invZ - M[0] - lZ;              // sum t*log t
        float ci  = S[3] * invZ - M[1] - logf(S[2]);      // sum t*log_softmax(lpi)
        float ct  = S[5] * invZ - M[2] - logf(S[4]);
        float cc  = S[7] * invZ - M[3] - logf(S[6]);
        g_contrib[i] = (2.0f * ent - ci - ct) * (0.5f / (float)BB)
                     + 0.2f * (ent - cc) * (1.0f / (float)BB);
    }
}

// ---------------- Kernel 3: final reduction + combine ------------------------
__global__ __launch_bounds__(512) void finalize_kernel(float* __restrict__ out) {
    int tid = threadIdx.x;
    int wave = tid >> 6, lane = tid & 63;
    float c = g_contrib[tid];
    float b = g_bceP[tid];
    float m = g_mskP[tid];
    __shared__ float red[8][3];
    float wc = wave_sum(c), wb = wave_sum(b), wm = wave_sum(m);
    if (lane == 0) { red[wave][0] = wc; red[wave][1] = wb; red[wave][2] = wm; }
    __syncthreads();
    if (tid == 0) {
        float C = 0.0f, Bs = 0.0f, Ms = 0.0f;
        #pragma unroll
        for (int w = 0; w < 8; ++w) { C += red[w][0]; Bs += red[w][1]; Ms += red[w][2]; }
        out[0] = C + 0.2f * (Bs / (Ms + 1e-8f));
    }
}

extern "C" void kernel_launch(void* const* d_in, const int* in_sizes, int n_in,
                              void* d_out, int out_size, void* d_ws, size_t ws_size,
                              hipStream_t stream) {
    const float* lpi = (const float*)d_in[0];   // logits_per_image [512,512]
    const float* lpt = (const float*)d_in[1];   // logits_per_text  [512,512]
    const float* cl  = (const float*)d_in[2];   // concepts_logits  [512,256]
    const float* cis = (const float*)d_in[3];   // concepts_image_similarity [512,512]
    const int*   mc  = (const int*)d_in[4];     // medical_concepts [512,256]

    (void)d_ws; (void)ws_size;   // unused: d_ws poison is unconditional (R6)

    float* out = (float*)d_out;

    pack_bce_kernel<<<BB, CC, 0, stream>>>(mc, cl);
    row_kernel<<<BB, CC, 0, stream>>>(lpi, lpt, cis);
    finalize_kernel<<<1, BB, 0, stream>>>(out);
}